// Round 4
// baseline (103.168 us; speedup 1.0000x reference)
//
#include <hip/hip_runtime.h>
#include <math.h>
#include <float.h>

#define BLOCK 256
#define GPS 32          // blocks per sample
#define BS 64           // batch

struct Partial { double s, d, p; unsigned cp, ch; };   // 32 B

// exp(v) for v >= 0 (v up to ~700) without libm f64 exp:
// exp(v) = 2^(v*log2e) = exp2f(frac) * 2^n, 2^n built via f64 exponent bits.
__device__ inline double exp_pos_d(float v) {
    float t = v * 1.44269504f;          // v*log2(e)
    float nf = rintf(t);
    float r = t - nf;                    // [-0.5, 0.5]
    float p = exp2f(r);                  // one v_exp_f32
    int n = (int)nf;
    n = n > 1020 ? 1020 : n;             // keep exponent field valid
    double scale = __longlong_as_double(((long long)(n + 1023)) << 52);
    return (double)p * scale;
}

__global__ __launch_bounds__(BLOCK) void k1_fused(
        const float* __restrict__ inp, const int* __restrict__ lab,
        Partial* __restrict__ parts, unsigned* __restrict__ counter,
        float* __restrict__ out, int N, int G) {
    const int bid = blockIdx.x;
    const int b = bid / G, g = bid % G;
    const int Nc = N / G;                     // 8192 elements per block
    const int tid = threadIdx.x;
    const float4* in4 = (const float4*)(inp + (size_t)b * 2u * (size_t)N);
    const int2*   lb2 = (const int2*)(lab + (size_t)b * (size_t)N);
    const int slot0 = (g * Nc) >> 1;          // float4 (== int2) slot of stripe start
    const int iters = Nc / (8 * BLOCK);       // 8 elements / thread / iter -> 4 iters

    double S = 0.0, D = 0.0;
    float psum = 0.0f;
    unsigned cp = 0, ch = 0;

    for (int it = 0; it < iters; ++it) {
        const int a = slot0 + it * (4 * BLOCK) + tid;
        float4 f0 = in4[a];
        float4 f1 = in4[a + BLOCK];
        float4 f2 = in4[a + 2 * BLOCK];
        float4 f3 = in4[a + 3 * BLOCK];
        int2   l0 = lb2[a];
        int2   l1 = lb2[a + BLOCK];
        int2   l2 = lb2[a + 2 * BLOCK];
        int2   l3 = lb2[a + 3 * BLOCK];
        const float xs[8] = { f0.y, f0.w, f1.y, f1.w, f2.y, f2.w, f3.y, f3.w };
        const int   ls[8] = { l0.x, l0.y, l1.x, l1.y, l2.x, l2.y, l3.x, l3.y };
        #pragma unroll
        for (int k = 0; k < 8; ++k) {
            const float x = xs[k];
            const bool pos = (ls[k] != 0);
            const float v = __expf(x);                        // prob
            cp   += pos ? 1u : 0u;
            psum += pos ? v : 0.0f;
            ch   |= (!pos && x > -0.69314718f) ? 1u : 0u;     // v>0.5 <=> x>ln(0.5)
            const double w = pos ? 0.0 : exp_pos_d(v);        // unnormalized softmax weight
            S += w;
            D += (double)v * w;
        }
    }

    // wave64 butterfly reduce (plain adds)
    double P = (double)psum;
    #pragma unroll
    for (int off = 32; off > 0; off >>= 1) {
        S  += __shfl_xor(S, off);
        D  += __shfl_xor(D, off);
        P  += __shfl_xor(P, off);
        cp += __shfl_xor(cp, off);
        ch |= __shfl_xor(ch, off);
    }

    __shared__ Partial sw[BLOCK / 64];
    __shared__ unsigned lastFlag;
    const int wid = tid >> 6, lane = tid & 63;
    if (lane == 0) { sw[wid].s = S; sw[wid].d = D; sw[wid].p = P; sw[wid].cp = cp; sw[wid].ch = ch; }
    __syncthreads();
    if (tid == 0) {
        for (int wv = 1; wv < BLOCK / 64; ++wv) {
            S += sw[wv].s; D += sw[wv].d; P += sw[wv].p; cp += sw[wv].cp; ch |= sw[wv].ch;
        }
        Partial o; o.s = S; o.d = D; o.p = P; o.cp = cp; o.ch = ch;
        parts[bid] = o;
        __threadfence();                          // device-scope release (L2 writeback)
        unsigned old = atomicAdd(counter, 1u);
        lastFlag = (old == (unsigned)(gridDim.x - 1)) ? 1u : 0u;
    }
    __syncthreads();
    if (!lastFlag) return;

    // ---- last block: per-sample losses + batch mean ----
    __threadfence();                              // acquire side
    const int s = tid >> 2, q = tid & 3;          // 4 threads per sample
    double S2 = 0.0, D2 = 0.0, P2 = 0.0;
    unsigned cp2 = 0, ch2 = 0;
    #pragma unroll
    for (int j = 0; j < GPS / 4; ++j) {
        Partial pp = parts[s * GPS + q + 4 * j];
        S2 += pp.s; D2 += pp.d; P2 += pp.p; cp2 += pp.cp; ch2 |= pp.ch;
    }
    #pragma unroll
    for (int off = 2; off > 0; off >>= 1) {       // reduce the 4-lane group
        S2  += __shfl_xor(S2, off);
        D2  += __shfl_xor(D2, off);
        P2  += __shfl_xor(P2, off);
        cp2 += __shfl_xor(cp2, off);
        ch2 |= __shfl_xor(ch2, off);
    }
    __shared__ float    sl[BS];
    __shared__ unsigned sv[BS];
    if (q == 0) {
        const double dist = (S2 > 0.0) ? (D2 / S2) : 0.0;   // neg softmax distance
        double z;
        if (cp2 > 0) z = 4.0 * (dist - P2 / (double)cp2 + 0.5);
        else         z = 4.0 * (dist - 0.5);
        // stable softplus in f64 (finite where f32 ref overflows to inf)
        const double sp = (z > 0.0) ? z + log1p(exp(-z)) : log1p(exp(z));
        sl[s] = (float)(sp * 0.25);
        sv[s] = (ch2 > 0) ? 1u : 0u;
    }
    __syncthreads();
    if (tid < 64) {
        float vv = (float)sv[tid];
        float l  = sl[tid] * vv;
        #pragma unroll
        for (int off = 32; off > 0; off >>= 1) {
            l  += __shfl_xor(l, off);
            vv += __shfl_xor(vv, off);
        }
        if (tid == 0) out[0] = (vv > 0.0f) ? (l / vv) : 0.0f;
    }
}

extern "C" void kernel_launch(void* const* d_in, const int* in_sizes, int n_in,
                              void* d_out, int out_size, void* d_ws, size_t ws_size,
                              hipStream_t stream) {
    const float* inp = (const float*)d_in[0];
    const int*   lab = (const int*)d_in[1];
    float* out = (float*)d_out;
    const int B = BS;
    const int N = in_sizes[1] / B;            // 262144

    Partial*  parts   = (Partial*)d_ws;                       // 2048 * 32 B = 64 KiB
    unsigned* counter = (unsigned*)((char*)d_ws + 65536);

    hipMemsetAsync(counter, 0, sizeof(unsigned), stream);     // capturable memset node
    k1_fused<<<B * GPS, BLOCK, 0, stream>>>(inp, lab, parts, counter, out, N, GPS);
}

// Round 5
// 38.502 us; speedup vs baseline: 2.6796x; 2.6796x over previous
//
#include <hip/hip_runtime.h>
#include <math.h>
#include <float.h>

#define BLOCK 256
#define GPS 32          // blocks per sample
#define BS 64           // batch

struct Partial { double s, d, p; unsigned cp, ch; };   // 32 B

// exp(v) for v >= 0 (v up to ~700) without libm f64 exp:
// exp(v) = 2^(v*log2e) = exp2f(frac) * 2^n, 2^n built via f64 exponent bits.
__device__ inline double exp_pos_d(float v) {
    float t = v * 1.44269504f;          // v*log2(e)
    float nf = rintf(t);
    float r = t - nf;                    // [-0.5, 0.5]
    float p = exp2f(r);                  // one v_exp_f32
    int n = (int)nf;
    n = n > 1020 ? 1020 : n;             // keep exponent field valid
    double scale = __longlong_as_double(((long long)(n + 1023)) << 52);
    return (double)p * scale;
}

__global__ __launch_bounds__(BLOCK) void k1_partials(
        const float* __restrict__ inp, const int* __restrict__ lab,
        Partial* __restrict__ parts, int N, int G) {
    const int bid = blockIdx.x;
    const int b = bid / G, g = bid % G;
    const int Nc = N / G;                     // 8192 elements per block
    const int tid = threadIdx.x;
    const float4* in4 = (const float4*)(inp + (size_t)b * 2u * (size_t)N);
    const int2*   lb2 = (const int2*)(lab + (size_t)b * (size_t)N);
    const int slot0 = (g * Nc) >> 1;          // float4 (== int2) slot of stripe start
    const int iters = Nc / (4 * BLOCK);       // 4 elements / thread / iter -> 8 iters

    double S = 0.0, D = 0.0;
    float psum = 0.0f;
    unsigned cp = 0, ch = 0;

    // ---- software-pipelined: prefetch iteration t+1 while processing t ----
    float4 f0 = in4[slot0 + tid];
    float4 f1 = in4[slot0 + BLOCK + tid];
    int2   l0 = lb2[slot0 + tid];
    int2   l1 = lb2[slot0 + BLOCK + tid];

#define PROCESS(F0, F1, L0, L1)                                               \
    {                                                                         \
        const float xs[4] = { F0.y, F0.w, F1.y, F1.w };                       \
        const int   ls[4] = { L0.x, L0.y, L1.x, L1.y };                       \
        _Pragma("unroll")                                                     \
        for (int k = 0; k < 4; ++k) {                                         \
            const float x = xs[k];                                            \
            const bool pos = (ls[k] != 0);                                    \
            const float v = __expf(x);                                        \
            cp   += pos ? 1u : 0u;                                            \
            psum += pos ? v : 0.0f;                                           \
            ch   |= (!pos && x > -0.69314718f) ? 1u : 0u;                     \
            const double w = pos ? 0.0 : exp_pos_d(v);                        \
            S += w;                                                           \
            D += (double)v * w;                                               \
        }                                                                     \
    }

    for (int it = 1; it < iters; ++it) {
        const int a = slot0 + it * (2 * BLOCK) + tid;
        float4 g0 = in4[a];
        float4 g1 = in4[a + BLOCK];
        int2   m0 = lb2[a];
        int2   m1 = lb2[a + BLOCK];
        PROCESS(f0, f1, l0, l1);
        f0 = g0; f1 = g1; l0 = m0; l1 = m1;
    }
    PROCESS(f0, f1, l0, l1);
#undef PROCESS

    // wave64 butterfly reduce (plain adds — no exp, no branches)
    double P = (double)psum;
    #pragma unroll
    for (int off = 32; off > 0; off >>= 1) {
        S  += __shfl_xor(S, off);
        D  += __shfl_xor(D, off);
        P  += __shfl_xor(P, off);
        cp += __shfl_xor(cp, off);
        ch |= __shfl_xor(ch, off);
    }

    __shared__ Partial sw[BLOCK / 64];
    const int wid = tid >> 6, lane = tid & 63;
    if (lane == 0) { sw[wid].s = S; sw[wid].d = D; sw[wid].p = P; sw[wid].cp = cp; sw[wid].ch = ch; }
    __syncthreads();
    if (tid == 0) {
        for (int wv = 1; wv < BLOCK / 64; ++wv) {
            S += sw[wv].s; D += sw[wv].d; P += sw[wv].p; cp += sw[wv].cp; ch |= sw[wv].ch;
        }
        Partial o; o.s = S; o.d = D; o.p = P; o.cp = cp; o.ch = ch;
        parts[bid] = o;
    }
}

// Fused per-sample loss + batch mean: one block of 1024 threads.
// 2048 partials -> 2/thread -> 16 threads per sample (segmented shfl reduce).
__global__ __launch_bounds__(1024) void k2_final(
        const Partial* __restrict__ parts, float* __restrict__ out) {
    const int tid = threadIdx.x;              // 0..1023
    Partial a = parts[2 * tid];
    Partial c = parts[2 * tid + 1];
    double S = a.s + c.s, D = a.d + c.d, P = a.p + c.p;
    unsigned cp = a.cp + c.cp, ch = a.ch | c.ch;

    #pragma unroll
    for (int off = 8; off > 0; off >>= 1) {   // reduce within 16-lane segments
        S  += __shfl_xor(S, off);
        D  += __shfl_xor(D, off);
        P  += __shfl_xor(P, off);
        cp += __shfl_xor(cp, off);
        ch |= __shfl_xor(ch, off);
    }

    __shared__ float    sl[BS];
    __shared__ unsigned sv[BS];
    const int sample = tid >> 4;
    if ((tid & 15) == 0) {
        const double dist = (S > 0.0) ? (D / S) : 0.0;   // neg softmax distance
        double z;
        if (cp > 0) z = 4.0 * (dist - P / (double)cp + 0.5);
        else        z = 4.0 * (dist - 0.5);
        // stable softplus in f64 (finite where f32 ref overflows to inf)
        const double sp = (z > 0.0) ? z + log1p(exp(-z)) : log1p(exp(z));
        sl[sample] = (float)(sp * 0.25);
        sv[sample] = (ch > 0) ? 1u : 0u;
    }
    __syncthreads();
    if (tid < 64) {
        float vv = (float)sv[tid];
        float l  = sl[tid] * vv;
        #pragma unroll
        for (int off = 32; off > 0; off >>= 1) {
            l  += __shfl_xor(l, off);
            vv += __shfl_xor(vv, off);
        }
        if (tid == 0) out[0] = (vv > 0.0f) ? (l / vv) : 0.0f;
    }
}

extern "C" void kernel_launch(void* const* d_in, const int* in_sizes, int n_in,
                              void* d_out, int out_size, void* d_ws, size_t ws_size,
                              hipStream_t stream) {
    const float* inp = (const float*)d_in[0];
    const int*   lab = (const int*)d_in[1];
    float* out = (float*)d_out;
    const int B = BS;
    const int N = in_sizes[1] / B;            // 262144

    Partial* parts = (Partial*)d_ws;          // 2048 * 32 B = 64 KiB

    k1_partials<<<B * GPS, BLOCK, 0, stream>>>(inp, lab, parts, N, GPS);
    k2_final<<<1, 1024, 0, stream>>>(parts, out);
}